// Round 1
// baseline (1016.498 us; speedup 1.0000x reference)
//
#include <hip/hip_runtime.h>
#include <cstdint>

#define NT   16384
#define DIN  1024
#define DHID 4096
#define DOUT 1024
#define NE   8
#define NMT  136   // 128-row m-tiles: NT/128 + NE
#define NMT2 72    // 256-row m-tiles: NT/256 + NE

typedef unsigned short u16;
typedef short bf16x8 __attribute__((ext_vector_type(8)));
typedef float f32x4  __attribute__((ext_vector_type(4)));

__device__ __forceinline__ u16 f2b(float f) {
  union { float f; unsigned u; } a; a.f = f;
  unsigned u = a.u;
  return (u16)((u + 0x7FFFu + ((u >> 16) & 1u)) >> 16);  // RNE
}

// async global->LDS, 16B per lane; LDS dst is wave-uniform base + lane*16
__device__ __forceinline__ void gl_lds16(const u16* g, u16* l) {
  __builtin_amdgcn_global_load_lds(
      (const __attribute__((address_space(1))) void*)g,
      (__attribute__((address_space(3))) void*)l,
      16, 0, 0);
}

__device__ __forceinline__ void barrier_raw() {
  asm volatile("" ::: "memory");
  __builtin_amdgcn_s_barrier();
  asm volatile("" ::: "memory");
}
__device__ __forceinline__ void lgkm0() {
  asm volatile("s_waitcnt lgkmcnt(0)" ::: "memory");
  __builtin_amdgcn_sched_barrier(0);   // rule #18: keep MFMAs below the wait
}
__device__ __forceinline__ void vm6() {
  asm volatile("s_waitcnt vmcnt(6)" ::: "memory");
}

// ---------------- router: logits, argmax, bf16 copy of x ----------------
__global__ void router_kernel(const float* __restrict__ x, const float* __restrict__ Wr,
                              const float* __restrict__ br, u16* __restrict__ Xb,
                              int* __restrict__ eidx, int* __restrict__ counts) {
  int t = blockIdx.x * 4 + (threadIdx.x >> 6);
  int lane = threadIdx.x & 63;
  const float4* xr = (const float4*)(x + (size_t)t * DIN);
  ushort4* xbr = (ushort4*)(Xb + (size_t)t * DIN);
  float acc[NE];
#pragma unroll
  for (int e = 0; e < NE; e++) acc[e] = 0.f;
#pragma unroll
  for (int i = 0; i < DIN / 256; i++) {   // 4 iters, 16B/lane x-loads
    int q = lane + i * 64;
    float4 xv = xr[q];
    ushort4 o;
    o.x = f2b(xv.x); o.y = f2b(xv.y); o.z = f2b(xv.z); o.w = f2b(xv.w);
    xbr[q] = o;
    const float* wp = Wr + (size_t)q * 4 * NE;
#pragma unroll
    for (int kk = 0; kk < 4; kk++) {
      float xs = (&xv.x)[kk];
      const float4 w0 = *(const float4*)(wp + kk * NE);
      const float4 w1 = *(const float4*)(wp + kk * NE + 4);
      acc[0] += xs * w0.x; acc[1] += xs * w0.y; acc[2] += xs * w0.z; acc[3] += xs * w0.w;
      acc[4] += xs * w1.x; acc[5] += xs * w1.y; acc[6] += xs * w1.z; acc[7] += xs * w1.w;
    }
  }
#pragma unroll
  for (int off = 32; off > 0; off >>= 1) {
#pragma unroll
    for (int e = 0; e < NE; e++) acc[e] += __shfl_down(acc[e], off, 64);
  }
  if (lane == 0) {
    int best = 0; float bv = acc[0] + br[0];
#pragma unroll
    for (int e = 1; e < NE; e++) {
      float v = acc[e] + br[e];
      if (v > bv) { bv = v; best = e; }   // strict > keeps first max (jnp.argmax)
    }
    eidx[t] = best;
    atomicAdd(&counts[best], 1);
  }
}

__global__ void zero_kernel(int* __restrict__ p) {
  if (threadIdx.x < 16) p[threadIdx.x] = 0;   // counts[8] + cursor[8]
}

// prefix-scan + build compact (expert, row-base, valid) tile maps (128 & 256)
__global__ void scan_kernel(const int* __restrict__ counts, int* __restrict__ offsets,
                            int4* __restrict__ tiles, int4* __restrict__ tiles2) {
  if (threadIdx.x == 0) {
    int s = 0, nt = 0, nt2 = 0;
    for (int e = 0; e < NE; e++) {
      int c = counts[e];
      offsets[e] = s;
      for (int m0 = 0; m0 < c; m0 += 128) {
        int v = c - m0; if (v > 128) v = 128;
        tiles[nt++] = make_int4(e, s + m0, v, 0);
      }
      for (int m0 = 0; m0 < c; m0 += 256) {
        int v = c - m0; if (v > 256) v = 256;
        tiles2[nt2++] = make_int4(e, s + m0, v, 0);
      }
      s += c;
    }
    offsets[NE] = s;
    while (nt < NMT) tiles[nt++] = make_int4(0, 0, 0, 0);
    while (nt2 < NMT2) tiles2[nt2++] = make_int4(0, 0, 0, 0);
  }
}

__global__ void scatter_kernel(const int* __restrict__ eidx, const int* __restrict__ offsets,
                               int* __restrict__ cursor, int* __restrict__ perm) {
  int t = blockIdx.x * blockDim.x + threadIdx.x;
  if (t >= NT) return;
  int e = eidx[t];
  int pos = offsets[e] + atomicAdd(&cursor[e], 1);
  perm[pos] = t;
}

// ------ fused convert fp32 W1[E][K][H],W2[E][K][H] -> bf16 Wt[E][H][K] ------
__global__ void transpose_cvt_all(const float* __restrict__ W1, const float* __restrict__ W2,
                                  u16* __restrict__ W1t, u16* __restrict__ W2t) {
  __shared__ float tile[64][65];
  int bid = blockIdx.x;
  const float* src; u16* dst; int K, H, k0, h0;
  if (bid < NE * 16 * 64) {                // W1: K=1024 (16 ktiles), H=4096 (64 htiles)
    int e = bid >> 10, rem = bid & 1023;
    K = DIN; H = DHID;
    k0 = (rem & 15) * 64; h0 = (rem >> 4) * 64;
    src = W1 + (size_t)e * DIN * DHID; dst = W1t + (size_t)e * DIN * DHID;
  } else {                                 // W2: K=4096 (64 ktiles), H=1024 (16 htiles)
    bid -= NE * 16 * 64;
    int e = bid >> 10, rem = bid & 1023;
    K = DHID; H = DOUT;
    k0 = (rem >> 4) * 64; h0 = (rem & 15) * 64;
    src = W2 + (size_t)e * DHID * DOUT; dst = W2t + (size_t)e * DHID * DOUT;
  }
  const int tid = threadIdx.x;
#pragma unroll
  for (int i = 0; i < 4; i++) {
    int idx = tid + i * 256;
    int r = idx >> 4;
    int c = (idx & 15) * 4;
    const float4 v = *(const float4*)(src + (size_t)(k0 + r) * H + h0 + c);
    tile[r][c] = v.x; tile[r][c + 1] = v.y; tile[r][c + 2] = v.z; tile[r][c + 3] = v.w;
  }
  __syncthreads();
#pragma unroll
  for (int i = 0; i < 4; i++) {
    int idx = tid + i * 256;
    int r = idx >> 4;
    int c = (idx & 15) * 4;
    ushort4 o;
    o.x = f2b(tile[c][r]); o.y = f2b(tile[c + 1][r]);
    o.z = f2b(tile[c + 2][r]); o.w = f2b(tile[c + 3][r]);
    *(ushort4*)(dst + (size_t)(h0 + r) * K + k0 + c) = o;
  }
}

// ---------------- GEMM2: 128x128 tile, BK=64, 2-phase (unchanged, proven) ----
template<bool GATHER_A, bool STORE_HIDDEN>
__global__ __launch_bounds__(256) void moe_gemm(
    const u16* __restrict__ A, const u16* __restrict__ Bt,
    const float* __restrict__ bias,
    const int* __restrict__ perm, const int4* __restrict__ tiles,
    u16* __restrict__ Hout, float* __restrict__ Fout,
    int K, int N) {
  const int4 ti = tiles[blockIdx.y];
  const int valid = ti.z;
  if (valid == 0) return;
  const int e = ti.x;
  const int base_p = ti.y;
  const int n0 = blockIdx.x * 128;

  __shared__ u16 sA[2 * 128 * 32];
  __shared__ u16 sB[2 * 128 * 32];

  const int tid = threadIdx.x;
  const int lane = tid & 63;
  const int wave = tid >> 6;
  const int wm = (wave >> 1) * 64;
  const int wn = (wave & 1) * 64;
  const int quad = lane >> 4;
  const int l15 = lane & 15;

  const int rr = lane >> 2;
  const int cb = (lane & 3) * 8;

  const int rA0 = wave * 16 + rr;
  const int rA1 = rA0 + 64;

  int pa0 = base_p + rA0; if (pa0 > NT - 1) pa0 = NT - 1;
  int pa1 = base_p + rA1; if (pa1 > NT - 1) pa1 = NT - 1;
  const int arow0 = GATHER_A ? perm[pa0] : pa0;
  const int arow1 = GATHER_A ? perm[pa1] : pa1;
  const u16* aptr0 = A + (size_t)arow0 * K + cb;
  const u16* aptr1 = A + (size_t)arow1 * K + cb;
  const u16* bptr0 = Bt + ((size_t)e * N + n0 + rA0) * K + cb;
  const u16* bptr1 = Bt + ((size_t)e * N + n0 + rA1) * K + cb;

  u16* dA0 = &sA[wave * 512];
  u16* dA1 = &sA[wave * 512 + 2048];
  u16* dB0 = &sB[wave * 512];
  u16* dB1 = &sB[wave * 512 + 2048];

  f32x4 acc[4][4];
#pragma unroll
  for (int mi = 0; mi < 4; mi++)
#pragma unroll
    for (int ni = 0; ni < 4; ni++)
      acc[mi][ni] = (f32x4){0.f, 0.f, 0.f, 0.f};

  const int kiters = K >> 6;
  for (int kt = 0; kt < kiters; kt++) {
    if (kt) __syncthreads();
    gl_lds16(aptr0,      dA0);
    gl_lds16(aptr1,      dA1);
    gl_lds16(bptr0,      dB0);
    gl_lds16(bptr1,      dB1);
    gl_lds16(aptr0 + 32, dA0 + 4096);
    gl_lds16(aptr1 + 32, dA1 + 4096);
    gl_lds16(bptr0 + 32, dB0 + 4096);
    gl_lds16(bptr1 + 32, dB1 + 4096);
    aptr0 += 64; aptr1 += 64; bptr0 += 64; bptr1 += 64;
    __syncthreads();

#pragma unroll
    for (int h = 0; h < 2; h++) {
      bf16x8 af[4], bfr[4];
#pragma unroll
      for (int mi = 0; mi < 4; mi++)
        af[mi] = *(const bf16x8*)&sA[h * 4096 + (wm + mi * 16 + l15) * 32 + quad * 8];
#pragma unroll
      for (int ni = 0; ni < 4; ni++)
        bfr[ni] = *(const bf16x8*)&sB[h * 4096 + (wn + ni * 16 + l15) * 32 + quad * 8];
#pragma unroll
      for (int mi = 0; mi < 4; mi++)
#pragma unroll
        for (int ni = 0; ni < 4; ni++)
          acc[mi][ni] = __builtin_amdgcn_mfma_f32_16x16x32_bf16(af[mi], bfr[ni], acc[mi][ni], 0, 0, 0);
    }
  }

  float bv[4];
#pragma unroll
  for (int ni = 0; ni < 4; ni++)
    bv[ni] = bias[(size_t)e * N + n0 + wn + ni * 16 + l15];

#pragma unroll
  for (int mi = 0; mi < 4; mi++) {
#pragma unroll
    for (int r = 0; r < 4; r++) {
      const int ml = wm + mi * 16 + quad * 4 + r;
      if (ml >= valid) continue;
      const int pp = base_p + ml;
      if (STORE_HIDDEN) {
        u16* orow = Hout + (size_t)pp * N + n0 + wn;
#pragma unroll
        for (int ni = 0; ni < 4; ni++) {
          float v = acc[mi][ni][r] + bv[ni];
          v = v > 0.f ? v : 0.f;
          orow[ni * 16 + l15] = f2b(v);
        }
      } else {
        const int token = perm[pp];
        float* orow = Fout + (size_t)token * N + n0 + wn;
#pragma unroll
        for (int ni = 0; ni < 4; ni++)
          orow[ni * 16 + l15] = acc[mi][ni][r] + bv[ni];
      }
    }
  }
}

// ---------------- GEMM1: 256x256 tile, BK=64, 8-phase counted-vmcnt ----------
// LDS regions (u16 units), 16KB each: X=even K-tiles, Y=odd; A row-major
// [128 rows][64 k] per region with T2 XOR swizzle byte^=((row&7)<<4).
#define RXA0 0
#define RXA1 8192
#define RXB0 16384
#define RXB1 24576
#define RYA0 32768
#define RYA1 40960
#define RYB0 49152
#define RYB1 57344

__global__ __launch_bounds__(512, 2) void moe_gemm1_8ph(
    const u16* __restrict__ A, const u16* __restrict__ Bt,
    const float* __restrict__ bias, const int* __restrict__ perm,
    const int4* __restrict__ tiles, u16* __restrict__ Hout) {
  const int4 ti = tiles[blockIdx.y];
  const int valid = ti.z;
  if (valid == 0) return;
  const int e = ti.x;
  const int base_p = ti.y;
  const int n0 = blockIdx.x * 256;

  __shared__ u16 lds[65536];   // 128 KiB

  const int tid = threadIdx.x;
  const int lane = tid & 63;
  const int w = tid >> 6;          // wave 0..7
  const int wr = w >> 2;           // 0..1 : m-half (128 rows)
  const int wc = w & 3;            // 0..3 : n-quarter (64 cols)
  const int quad = lane >> 4;
  const int l15 = lane & 15;

  // ---- staging geometry: issue s covers region rows s*64 + tid/8 ----
  const int srow = tid >> 3;                               // 0..63
  const int klog = ((tid & 7) << 3) ^ ((srow & 7) << 3);   // elements, pre-inverse-swizzled
  int p0 = base_p + srow;        if (p0 > NT - 1) p0 = NT - 1;
  int p1 = base_p + 64 + srow;   if (p1 > NT - 1) p1 = NT - 1;
  int p2 = base_p + 128 + srow;  if (p2 > NT - 1) p2 = NT - 1;
  int p3 = base_p + 192 + srow;  if (p3 > NT - 1) p3 = NT - 1;
  const u16* pA00 = A + (size_t)perm[p0] * DIN + klog;   // region A0, issue 0
  const u16* pA01 = A + (size_t)perm[p1] * DIN + klog;   // region A0, issue 1
  const u16* pA10 = A + (size_t)perm[p2] * DIN + klog;   // region A1, issue 0
  const u16* pA11 = A + (size_t)perm[p3] * DIN + klog;
  const u16* pB00 = Bt + ((size_t)e * DHID + n0 + srow)       * DIN + klog;
  const u16* pB01 = Bt + ((size_t)e * DHID + n0 + 64 + srow)  * DIN + klog;
  const u16* pB10 = Bt + ((size_t)e * DHID + n0 + 128 + srow) * DIN + klog;
  const u16* pB11 = Bt + ((size_t)e * DHID + n0 + 192 + srow) * DIN + klog;

#define STG(RB, P0, P1, KO) \
  do { gl_lds16((P0) + (KO), &lds[(RB) + w * 512]); \
       gl_lds16((P1) + (KO), &lds[(RB) + 4096 + w * 512]); } while (0)

  // prologue: X=tile0 (4 halves), Y=tile1 (B0,B1,A0) -> 14 issues; drain to 6
  STG(RXA0, pA00, pA01, 0);
  STG(RXA1, pA10, pA11, 0);
  STG(RXB0, pB00, pB01, 0);
  STG(RXB1, pB10, pB11, 0);
  STG(RYB0, pB00, pB01, 64);
  STG(RYB1, pB10, pB11, 64);
  STG(RYA0, pA00, pA01, 64);
  vm6();
  barrier_raw();

  const int aX = RXA0 + wr * 8192;
  const int bX = RXB0 + (wc >> 1) * 8192;
  const int aY = RYA0 + wr * 8192;
  const int bY = RYB0 + (wc >> 1) * 8192;
  const int swz = (l15 & 7) << 3;          // elements
  const int brow = (wc & 1) * 64 + l15;

  bf16x8 aF[4][2], bF[4][2];
  f32x4 acc[8][4];
#pragma unroll
  for (int i = 0; i < 8; i++)
#pragma unroll
    for (int j2 = 0; j2 < 4; j2++) acc[i][j2] = (f32x4){0.f, 0.f, 0.f, 0.f};

#define RDA(BASE, MH) do { _Pragma("unroll") \
  for (int mi = 0; mi < 4; mi++) { _Pragma("unroll") \
    for (int h = 0; h < 2; h++) \
      aF[mi][h] = *(const bf16x8*)&lds[(BASE) + ((MH) * 64 + mi * 16 + l15) * 64 + \
                                       ((h * 32 + quad * 8) ^ swz)]; } } while (0)

#define RDB(BASE) do { _Pragma("unroll") \
  for (int ni = 0; ni < 4; ni++) { _Pragma("unroll") \
    for (int h = 0; h < 2; h++) \
      bF[ni][h] = *(const bf16x8*)&lds[(BASE) + (brow + ni * 16) * 64 + \
                                       ((h * 32 + quad * 8) ^ swz)]; } } while (0)

#define MM(MH, NB) do { __builtin_amdgcn_s_setprio(1); _Pragma("unroll") \
  for (int mi = 0; mi < 4; mi++) { _Pragma("unroll") \
    for (int ni = 0; ni < 2; ni++) { _Pragma("unroll") \
      for (int h = 0; h < 2; h++) \
        acc[(MH) * 4 + mi][(NB) + ni] = __builtin_amdgcn_mfma_f32_16x16x32_bf16( \
            aF[mi][h], bF[(NB) + ni][h], acc[(MH) * 4 + mi][(NB) + ni], 0, 0, 0); } } \
  __builtin_amdgcn_s_setprio(0); } while (0)

  const int NITER = DIN / 128;   // 8 iterations; K-tiles 0..15
  for (int j = 0; j < NITER; j++) {
    const int ky1 = (2 * j + 1) * 64;
    int t2 = 2 * j + 2; if (t2 > 15) t2 = 15;   // dead-stage clamp at tail
    int t3 = 2 * j + 3; if (t3 > 15) t3 = 15;
    const int kx = t2 * 64, ky2 = t3 * 64;
    // P1: reads X.A(lo) + all X.B; stage Y.A1 (tile 2j+1)
    RDA(aX, 0); RDB(bX);
    STG(RYA1, pA10, pA11, ky1);
    barrier_raw(); lgkm0();
    MM(0, 0);
    barrier_raw();
    // P2: stage X.B0 (tile 2j+2)
    STG(RXB0, pB00, pB01, kx);
    barrier_raw(); lgkm0();
    MM(0, 2);
    barrier_raw();
    // P3: reads X.A(hi); stage X.B1
    RDA(aX, 1);
    STG(RXB1, pB10, pB11, kx);
    barrier_raw(); lgkm0();
    MM(1, 2);
    barrier_raw();
    // P4: stage X.A0; counted drain
    STG(RXA0, pA00, pA01, kx);
    barrier_raw(); lgkm0();
    MM(1, 0);
    vm6();
    barrier_raw();
    // P5: reads Y.A(lo) + all Y.B; stage X.A1
    RDA(aY, 0); RDB(bY);
    STG(RXA1, pA10, pA11, kx);
    barrier_raw(); lgkm0();
    MM(0, 0);
    barrier_raw();
    // P6: stage Y.B0 (tile 2j+3)
    STG(RYB0, pB00, pB01, ky2);
    barrier_raw(); lgkm0();
    MM(0, 2);
    barrier_raw();
    // P7: reads Y.A(hi); stage Y.B1
    RDA(aY, 1);
    STG(RYB1, pB10, pB11, ky2);
    barrier_raw(); lgkm0();
    MM(1, 2);
    barrier_raw();
    // P8: stage Y.A0; counted drain
    STG(RYA0, pA00, pA01, ky2);
    barrier_raw(); lgkm0();
    MM(1, 0);
    vm6();
    barrier_raw();
  }

  // epilogue: bias + relu + bf16 store (same C/D layout as proven kernel)
  const int col0 = n0 + wc * 64;
  float bv[4];
#pragma unroll
  for (int ni = 0; ni < 4; ni++)
    bv[ni] = bias[(size_t)e * DHID + col0 + ni * 16 + l15];
#pragma unroll
  for (int mi8 = 0; mi8 < 8; mi8++) {
#pragma unroll
    for (int r = 0; r < 4; r++) {
      const int ml = wr * 128 + mi8 * 16 + quad * 4 + r;
      if (ml >= valid) continue;
      u16* orow = Hout + (size_t)(base_p + ml) * DHID + col0;
#pragma unroll
      for (int ni = 0; ni < 4; ni++) {
        float v = acc[mi8][ni][r] + bv[ni];
        v = v > 0.f ? v : 0.f;
        orow[ni * 16 + l15] = f2b(v);
      }
    }
  }
#undef STG
#undef RDA
#undef RDB
#undef MM
}

__global__ void sentinel_kernel(float* __restrict__ out, int n) {
  int i = blockIdx.x * blockDim.x + threadIdx.x;
  if (i < n) out[i] = 31337.0f;
}

extern "C" void kernel_launch(void* const* d_in, const int* in_sizes, int n_in,
                              void* d_out, int out_size, void* d_ws, size_t ws_size,
                              hipStream_t stream) {
  const float* x  = (const float*)d_in[0];
  const float* Wr = (const float*)d_in[1];
  const float* br = (const float*)d_in[2];
  const float* W1 = (const float*)d_in[3];
  const float* b1 = (const float*)d_in[4];
  const float* W2 = (const float*)d_in[5];
  const float* b2 = (const float*)d_in[6];
  float* out = (float*)d_out;

  const size_t szXb  = (size_t)NT * DIN * 2;
  const size_t szW1t = (size_t)NE * DIN * DHID * 2;
  const size_t szW2t = (size_t)NE * DHID * DOUT * 2;
  const size_t szHid = (size_t)NT * DHID * 2;
  char* ws = (char*)d_ws;
  u16* Xb   = (u16*)ws;
  u16* W1t  = (u16*)(ws + szXb);
  u16* W2t  = (u16*)(ws + szXb + szW1t);
  u16* Hid  = (u16*)(ws + szXb + szW1t + szW2t);
  int* perm = (int*)(ws + szXb + szW1t + szW2t + szHid);
  int* eidx = perm + NT;
  int* ctrl = eidx + NT;
  int* counts  = ctrl;
  int* cursor  = ctrl + 8;
  int* offsets = ctrl + 16;
  int4* tiles   = (int4*)(ctrl + 32);
  int4* tiles2  = tiles + NMT;     // 256-row tile map; (136+72)*16B fits the 4KB pad
  const size_t NEED = szXb + szW1t + szW2t + szHid + (size_t)NT * 4 * 2 + 4096;

  if (ws_size < NEED) {
    sentinel_kernel<<<(out_size + 255) / 256, 256, 0, stream>>>(out, out_size);
    return;
  }

  zero_kernel<<<1, 64, 0, stream>>>(ctrl);
  transpose_cvt_all<<<NE * 16 * 64 * 2, 256, 0, stream>>>(W1, W2, W1t, W2t);
  router_kernel<<<NT / 4, 256, 0, stream>>>(x, Wr, br, Xb, eidx, counts);
  scan_kernel<<<1, 64, 0, stream>>>(counts, offsets, tiles, tiles2);
  scatter_kernel<<<NT / 256, 256, 0, stream>>>(eidx, offsets, cursor, perm);

  // GEMM1: hidden[p][h] = relu(Xb[perm[p]] @ W1[e] + b1[e]), bf16 — 8-phase 256^2
  moe_gemm1_8ph<<<dim3(DHID / 256, NMT2), 512, 0, stream>>>(
      Xb, W1t, b1, perm, tiles2, Hid);
  // GEMM2: out[perm[p]][o] = hidden[p] @ W2[e] + b2[e], fp32 — 2-phase 128^2
  moe_gemm<false, false><<<dim3(DOUT / 128, NMT), 256, 0, stream>>>(
      Hid, W2t, b2, perm, tiles, nullptr, out, DHID, DOUT);
}

// Round 2
// 991.178 us; speedup vs baseline: 1.0255x; 1.0255x over previous
//
#include <hip/hip_runtime.h>
#include <cstdint>

#define NT   16384
#define DIN  1024
#define DHID 4096
#define DOUT 1024
#define NE   8
#define NMT  136   // 128-row m-tiles: NT/128 + NE  (= 8 XCD groups x 17)
#define NMT2 72    // 256-row m-tiles: NT/256 + NE  (= 8 XCD groups x 9)

typedef unsigned short u16;
typedef short bf16x8 __attribute__((ext_vector_type(8)));
typedef float f32x4  __attribute__((ext_vector_type(4)));

__device__ __forceinline__ u16 f2b(float f) {
  union { float f; unsigned u; } a; a.f = f;
  unsigned u = a.u;
  return (u16)((u + 0x7FFFu + ((u >> 16) & 1u)) >> 16);  // RNE
}

// async global->LDS, 16B per lane; LDS dst is wave-uniform base + lane*16
__device__ __forceinline__ void gl_lds16(const u16* g, u16* l) {
  __builtin_amdgcn_global_load_lds(
      (const __attribute__((address_space(1))) void*)g,
      (__attribute__((address_space(3))) void*)l,
      16, 0, 0);
}

__device__ __forceinline__ void barrier_raw() {
  asm volatile("" ::: "memory");
  __builtin_amdgcn_s_barrier();
  asm volatile("" ::: "memory");
}
__device__ __forceinline__ void lgkm0() {
  asm volatile("s_waitcnt lgkmcnt(0)" ::: "memory");
  __builtin_amdgcn_sched_barrier(0);   // rule #18: keep MFMAs below the wait
}
__device__ __forceinline__ void vm6() {
  asm volatile("s_waitcnt vmcnt(6)" ::: "memory");
}

// ---------------- router: logits, argmax, bf16 copy of x ----------------
__global__ void router_kernel(const float* __restrict__ x, const float* __restrict__ Wr,
                              const float* __restrict__ br, u16* __restrict__ Xb,
                              int* __restrict__ eidx, int* __restrict__ counts) {
  int t = blockIdx.x * 4 + (threadIdx.x >> 6);
  int lane = threadIdx.x & 63;
  const float4* xr = (const float4*)(x + (size_t)t * DIN);
  ushort4* xbr = (ushort4*)(Xb + (size_t)t * DIN);
  float acc[NE];
#pragma unroll
  for (int e = 0; e < NE; e++) acc[e] = 0.f;
#pragma unroll
  for (int i = 0; i < DIN / 256; i++) {   // 4 iters, 16B/lane x-loads
    int q = lane + i * 64;
    float4 xv = xr[q];
    ushort4 o;
    o.x = f2b(xv.x); o.y = f2b(xv.y); o.z = f2b(xv.z); o.w = f2b(xv.w);
    xbr[q] = o;
    const float* wp = Wr + (size_t)q * 4 * NE;
#pragma unroll
    for (int kk = 0; kk < 4; kk++) {
      float xs = (&xv.x)[kk];
      const float4 w0 = *(const float4*)(wp + kk * NE);
      const float4 w1 = *(const float4*)(wp + kk * NE + 4);
      acc[0] += xs * w0.x; acc[1] += xs * w0.y; acc[2] += xs * w0.z; acc[3] += xs * w0.w;
      acc[4] += xs * w1.x; acc[5] += xs * w1.y; acc[6] += xs * w1.z; acc[7] += xs * w1.w;
    }
  }
#pragma unroll
  for (int off = 32; off > 0; off >>= 1) {
#pragma unroll
    for (int e = 0; e < NE; e++) acc[e] += __shfl_down(acc[e], off, 64);
  }
  if (lane == 0) {
    int best = 0; float bv = acc[0] + br[0];
#pragma unroll
    for (int e = 1; e < NE; e++) {
      float v = acc[e] + br[e];
      if (v > bv) { bv = v; best = e; }   // strict > keeps first max (jnp.argmax)
    }
    eidx[t] = best;
    atomicAdd(&counts[best], 1);
  }
}

__global__ void zero_kernel(int* __restrict__ p) {
  if (threadIdx.x < 16) p[threadIdx.x] = 0;   // counts[8] + cursor[8]
}

// prefix-scan + build compact (expert, row-base, valid) tile maps (128 & 256)
__global__ void scan_kernel(const int* __restrict__ counts, int* __restrict__ offsets,
                            int4* __restrict__ tiles, int4* __restrict__ tiles2) {
  if (threadIdx.x == 0) {
    int s = 0, nt = 0, nt2 = 0;
    for (int e = 0; e < NE; e++) {
      int c = counts[e];
      offsets[e] = s;
      for (int m0 = 0; m0 < c; m0 += 128) {
        int v = c - m0; if (v > 128) v = 128;
        tiles[nt++] = make_int4(e, s + m0, v, 0);
      }
      for (int m0 = 0; m0 < c; m0 += 256) {
        int v = c - m0; if (v > 256) v = 256;
        tiles2[nt2++] = make_int4(e, s + m0, v, 0);
      }
      s += c;
    }
    offsets[NE] = s;
    while (nt < NMT) tiles[nt++] = make_int4(0, 0, 0, 0);
    while (nt2 < NMT2) tiles2[nt2++] = make_int4(0, 0, 0, 0);
  }
}

__global__ void scatter_kernel(const int* __restrict__ eidx, const int* __restrict__ offsets,
                               int* __restrict__ cursor, int* __restrict__ perm) {
  int t = blockIdx.x * blockDim.x + threadIdx.x;
  if (t >= NT) return;
  int e = eidx[t];
  int pos = offsets[e] + atomicAdd(&cursor[e], 1);
  perm[pos] = t;
}

// ------ fused convert fp32 W1[E][K][H],W2[E][K][H] -> bf16 Wt[E][H][K] ------
__global__ void transpose_cvt_all(const float* __restrict__ W1, const float* __restrict__ W2,
                                  u16* __restrict__ W1t, u16* __restrict__ W2t) {
  __shared__ float tile[64][65];
  int bid = blockIdx.x;
  const float* src; u16* dst; int K, H, k0, h0;
  if (bid < NE * 16 * 64) {                // W1: K=1024 (16 ktiles), H=4096 (64 htiles)
    int e = bid >> 10, rem = bid & 1023;
    K = DIN; H = DHID;
    k0 = (rem & 15) * 64; h0 = (rem >> 4) * 64;
    src = W1 + (size_t)e * DIN * DHID; dst = W1t + (size_t)e * DIN * DHID;
  } else {                                 // W2: K=4096 (64 ktiles), H=1024 (16 htiles)
    bid -= NE * 16 * 64;
    int e = bid >> 10, rem = bid & 1023;
    K = DHID; H = DOUT;
    k0 = (rem >> 4) * 64; h0 = (rem & 15) * 64;
    src = W2 + (size_t)e * DHID * DOUT; dst = W2t + (size_t)e * DHID * DOUT;
  }
  const int tid = threadIdx.x;
#pragma unroll
  for (int i = 0; i < 4; i++) {
    int idx = tid + i * 256;
    int r = idx >> 4;
    int c = (idx & 15) * 4;
    const float4 v = *(const float4*)(src + (size_t)(k0 + r) * H + h0 + c);
    tile[r][c] = v.x; tile[r][c + 1] = v.y; tile[r][c + 2] = v.z; tile[r][c + 3] = v.w;
  }
  __syncthreads();
#pragma unroll
  for (int i = 0; i < 4; i++) {
    int idx = tid + i * 256;
    int r = idx >> 4;
    int c = (idx & 15) * 4;
    ushort4 o;
    o.x = f2b(tile[c][r]); o.y = f2b(tile[c + 1][r]);
    o.z = f2b(tile[c + 2][r]); o.w = f2b(tile[c + 3][r]);
    *(ushort4*)(dst + (size_t)(h0 + r) * K + k0 + c) = o;
  }
}

// ---------------- GEMM2: 128x128 tile, BK=64, 2-phase + XCD remap ----------
// Grid: flat 1088 blocks. bid&7 = XCD group g; each XCD owns m-tiles
// [g*17, g*17+17), n fastest -> A m-panel (Hid) fetched once per XCD.
__global__ __launch_bounds__(256) void moe_gemm2(
    const u16* __restrict__ A, const u16* __restrict__ Bt,
    const float* __restrict__ bias,
    const int* __restrict__ perm, const int4* __restrict__ tiles,
    float* __restrict__ Fout) {
  const int bid = blockIdx.x;
  const int g = bid & 7;
  const int r_ = bid >> 3;          // 0..135
  const int n = r_ & 7;             // n fastest within XCD
  const int j = r_ >> 3;            // 0..16
  const int m = g * 17 + j;
  const int4 ti = tiles[m];
  const int valid = ti.z;
  if (valid == 0) return;
  const int e = ti.x;
  const int base_p = ti.y;
  const int n0 = n * 128;
  const int K = DHID, N = DOUT;

  __shared__ u16 sA[2 * 128 * 32];
  __shared__ u16 sB[2 * 128 * 32];

  const int tid = threadIdx.x;
  const int lane = tid & 63;
  const int wave = tid >> 6;
  const int wm = (wave >> 1) * 64;
  const int wn = (wave & 1) * 64;
  const int quad = lane >> 4;
  const int l15 = lane & 15;
  const bool alive = (wm < valid);   // dead-wave skip (tail tiles)

  const int rr = lane >> 2;
  const int cb = (lane & 3) * 8;

  const int rA0 = wave * 16 + rr;
  const int rA1 = rA0 + 64;

  int pa0 = base_p + rA0; if (pa0 > NT - 1) pa0 = NT - 1;
  int pa1 = base_p + rA1; if (pa1 > NT - 1) pa1 = NT - 1;
  const u16* aptr0 = A + (size_t)pa0 * K + cb;
  const u16* aptr1 = A + (size_t)pa1 * K + cb;
  const u16* bptr0 = Bt + ((size_t)e * N + n0 + rA0) * K + cb;
  const u16* bptr1 = Bt + ((size_t)e * N + n0 + rA1) * K + cb;

  u16* dA0 = &sA[wave * 512];
  u16* dA1 = &sA[wave * 512 + 2048];
  u16* dB0 = &sB[wave * 512];
  u16* dB1 = &sB[wave * 512 + 2048];

  f32x4 acc[4][4];
#pragma unroll
  for (int mi = 0; mi < 4; mi++)
#pragma unroll
    for (int ni = 0; ni < 4; ni++)
      acc[mi][ni] = (f32x4){0.f, 0.f, 0.f, 0.f};

  const int kiters = K >> 6;
  for (int kt = 0; kt < kiters; kt++) {
    if (kt) __syncthreads();
    gl_lds16(aptr0,      dA0);
    gl_lds16(aptr1,      dA1);
    gl_lds16(bptr0,      dB0);
    gl_lds16(bptr1,      dB1);
    gl_lds16(aptr0 + 32, dA0 + 4096);
    gl_lds16(aptr1 + 32, dA1 + 4096);
    gl_lds16(bptr0 + 32, dB0 + 4096);
    gl_lds16(bptr1 + 32, dB1 + 4096);
    aptr0 += 64; aptr1 += 64; bptr0 += 64; bptr1 += 64;
    __syncthreads();

    if (alive) {
#pragma unroll
      for (int h = 0; h < 2; h++) {
        bf16x8 af[4], bfr[4];
#pragma unroll
        for (int mi = 0; mi < 4; mi++)
          af[mi] = *(const bf16x8*)&sA[h * 4096 + (wm + mi * 16 + l15) * 32 + quad * 8];
#pragma unroll
        for (int ni = 0; ni < 4; ni++)
          bfr[ni] = *(const bf16x8*)&sB[h * 4096 + (wn + ni * 16 + l15) * 32 + quad * 8];
#pragma unroll
        for (int mi = 0; mi < 4; mi++)
#pragma unroll
          for (int ni = 0; ni < 4; ni++)
            acc[mi][ni] = __builtin_amdgcn_mfma_f32_16x16x32_bf16(af[mi], bfr[ni], acc[mi][ni], 0, 0, 0);
      }
    }
  }
  if (!alive) return;   // after last barrier use; uniform per wave

  float bv[4];
#pragma unroll
  for (int ni = 0; ni < 4; ni++)
    bv[ni] = bias[(size_t)e * N + n0 + wn + ni * 16 + l15];

#pragma unroll
  for (int mi = 0; mi < 4; mi++) {
#pragma unroll
    for (int r = 0; r < 4; r++) {
      const int ml = wm + mi * 16 + quad * 4 + r;
      if (ml >= valid) continue;
      const int token = perm[base_p + ml];
      float* orow = Fout + (size_t)token * N + n0 + wn;
#pragma unroll
      for (int ni = 0; ni < 4; ni++)
        orow[ni * 16 + l15] = acc[mi][ni][r] + bv[ni];
    }
  }
}

// ---------------- GEMM1: 256x256 tile, BK=64, 8-phase counted-vmcnt ----------
// LDS regions (u16 units), 16KB each: X=even K-tiles, Y=odd; A row-major
// [128 rows][64 k] per region with T2 XOR swizzle byte^=((row&7)<<4).
#define RXA0 0
#define RXA1 8192
#define RXB0 16384
#define RXB1 24576
#define RYA0 32768
#define RYA1 40960
#define RYB0 49152
#define RYB1 57344

__global__ __launch_bounds__(512, 2) void moe_gemm1_8ph(
    const u16* __restrict__ A, const u16* __restrict__ Bt,
    const float* __restrict__ bias, const int* __restrict__ perm,
    const int4* __restrict__ tiles, u16* __restrict__ Hout) {
  // XCD remap: bid&7 = XCD g; XCD owns m-tiles [g*9, g*9+9), n fastest.
  const int bid = blockIdx.x;
  const int g = bid & 7;
  const int r_ = bid >> 3;          // 0..143
  const int n = r_ & 15;
  const int j_ = r_ >> 4;           // 0..8
  const int m = g * 9 + j_;
  const int4 ti = tiles[m];
  const int valid = ti.z;
  if (valid == 0) return;
  const int e = ti.x;
  const int base_p = ti.y;
  const int n0 = n * 256;

  __shared__ u16 lds[65536];   // 128 KiB

  const int tid = threadIdx.x;
  const int lane = tid & 63;
  const int w = tid >> 6;          // wave 0..7
  const int wr = w >> 2;           // 0..1 : m-half (128 rows)
  const int wc = w & 3;            // 0..3 : n-quarter (64 cols)
  const int quad = lane >> 4;
  const int l15 = lane & 15;
  const bool aliveLo = (valid > wr * 128);        // rows wr*128 + [0,64)
  const bool aliveHi = (valid > wr * 128 + 64);   // rows wr*128 + [64,128)

  // ---- staging geometry: issue s covers region rows s*64 + tid/8 ----
  const int srow = tid >> 3;                               // 0..63
  const int klog = ((tid & 7) << 3) ^ ((srow & 7) << 3);   // elements, pre-inverse-swizzled
  int p0 = base_p + srow;        if (p0 > NT - 1) p0 = NT - 1;
  int p1 = base_p + 64 + srow;   if (p1 > NT - 1) p1 = NT - 1;
  int p2 = base_p + 128 + srow;  if (p2 > NT - 1) p2 = NT - 1;
  int p3 = base_p + 192 + srow;  if (p3 > NT - 1) p3 = NT - 1;
  const u16* pA00 = A + (size_t)perm[p0] * DIN + klog;   // region A0, issue 0
  const u16* pA01 = A + (size_t)perm[p1] * DIN + klog;   // region A0, issue 1
  const u16* pA10 = A + (size_t)perm[p2] * DIN + klog;   // region A1, issue 0
  const u16* pA11 = A + (size_t)perm[p3] * DIN + klog;
  const u16* pB00 = Bt + ((size_t)e * DHID + n0 + srow)       * DIN + klog;
  const u16* pB01 = Bt + ((size_t)e * DHID + n0 + 64 + srow)  * DIN + klog;
  const u16* pB10 = Bt + ((size_t)e * DHID + n0 + 128 + srow) * DIN + klog;
  const u16* pB11 = Bt + ((size_t)e * DHID + n0 + 192 + srow) * DIN + klog;

#define STG(RB, P0, P1, KO) \
  do { gl_lds16((P0) + (KO), &lds[(RB) + w * 512]); \
       gl_lds16((P1) + (KO), &lds[(RB) + 4096 + w * 512]); } while (0)

  // prologue: X=tile0 (4 halves), Y=tile1 (B0,B1,A0) -> 14 issues; drain to 6
  STG(RXA0, pA00, pA01, 0);
  STG(RXA1, pA10, pA11, 0);
  STG(RXB0, pB00, pB01, 0);
  STG(RXB1, pB10, pB11, 0);
  STG(RYB0, pB00, pB01, 64);
  STG(RYB1, pB10, pB11, 64);
  STG(RYA0, pA00, pA01, 64);
  vm6();
  barrier_raw();

  const int aX = RXA0 + wr * 8192;
  const int bX = RXB0 + (wc >> 1) * 8192;
  const int aY = RYA0 + wr * 8192;
  const int bY = RYB0 + (wc >> 1) * 8192;
  const int swz = (l15 & 7) << 3;          // elements
  const int brow = (wc & 1) * 64 + l15;

  bf16x8 aF[4][2], bF[4][2];
  f32x4 acc[8][4];
#pragma unroll
  for (int i = 0; i < 8; i++)
#pragma unroll
    for (int j2 = 0; j2 < 4; j2++) acc[i][j2] = (f32x4){0.f, 0.f, 0.f, 0.f};

#define RDA(BASE, MH) do { if ((MH) ? aliveHi : aliveLo) { _Pragma("unroll") \
  for (int mi = 0; mi < 4; mi++) { _Pragma("unroll") \
    for (int h = 0; h < 2; h++) \
      aF[mi][h] = *(const bf16x8*)&lds[(BASE) + ((MH) * 64 + mi * 16 + l15) * 64 + \
                                       ((h * 32 + quad * 8) ^ swz)]; } } } while (0)

#define RDB2(BASE, NB) do { if (aliveLo) { _Pragma("unroll") \
  for (int ni = 0; ni < 2; ni++) { _Pragma("unroll") \
    for (int h = 0; h < 2; h++) \
      bF[(NB) + ni][h] = *(const bf16x8*)&lds[(BASE) + (brow + ((NB) + ni) * 16) * 64 + \
                                              ((h * 32 + quad * 8) ^ swz)]; } } } while (0)

#define MM(MH, NB) do { if ((MH) ? aliveHi : aliveLo) { \
  __builtin_amdgcn_s_setprio(1); _Pragma("unroll") \
  for (int mi = 0; mi < 4; mi++) { _Pragma("unroll") \
    for (int ni = 0; ni < 2; ni++) { _Pragma("unroll") \
      for (int h = 0; h < 2; h++) \
        acc[(MH) * 4 + mi][(NB) + ni] = __builtin_amdgcn_mfma_f32_16x16x32_bf16( \
            aF[mi][h], bF[(NB) + ni][h], acc[(MH) * 4 + mi][(NB) + ni], 0, 0, 0); } } \
  __builtin_amdgcn_s_setprio(0); } } while (0)

  const int NITER = DIN / 128;   // 8 iterations; K-tiles 0..15
  for (int j = 0; j < NITER; j++) {
    const int ky1 = (2 * j + 1) * 64;
    int t2 = 2 * j + 2; if (t2 > 15) t2 = 15;   // dead-stage clamp at tail
    int t3 = 2 * j + 3; if (t3 > 15) t3 = 15;
    const int kx = t2 * 64, ky2 = t3 * 64;
    // P1: reads X.A(lo) + X.B[0:1]; stage Y.A1 (tile 2j+1)
    RDA(aX, 0); RDB2(bX, 0);
    STG(RYA1, pA10, pA11, ky1);
    barrier_raw(); lgkm0();
    MM(0, 0);
    barrier_raw();
    // P2: reads X.B[2:3]; stage X.B0 (tile 2j+2)
    RDB2(bX, 2);
    STG(RXB0, pB00, pB01, kx);
    barrier_raw(); lgkm0();
    MM(0, 2);
    barrier_raw();
    // P3: reads X.A(hi); stage X.B1
    RDA(aX, 1);
    STG(RXB1, pB10, pB11, kx);
    barrier_raw(); lgkm0();
    MM(1, 2);
    barrier_raw();
    // P4: stage X.A0; counted drain
    STG(RXA0, pA00, pA01, kx);
    barrier_raw(); lgkm0();
    MM(1, 0);
    vm6();
    barrier_raw();
    // P5: reads Y.A(lo) + Y.B[0:1]; stage X.A1
    RDA(aY, 0); RDB2(bY, 0);
    STG(RXA1, pA10, pA11, kx);
    barrier_raw(); lgkm0();
    MM(0, 0);
    barrier_raw();
    // P6: reads Y.B[2:3]; stage Y.B0 (tile 2j+3)
    RDB2(bY, 2);
    STG(RYB0, pB00, pB01, ky2);
    barrier_raw(); lgkm0();
    MM(0, 2);
    barrier_raw();
    // P7: reads Y.A(hi); stage Y.B1
    RDA(aY, 1);
    STG(RYB1, pB10, pB11, ky2);
    barrier_raw(); lgkm0();
    MM(1, 2);
    barrier_raw();
    // P8: stage Y.A0; counted drain
    STG(RYA0, pA00, pA01, ky2);
    barrier_raw(); lgkm0();
    MM(1, 0);
    vm6();
    barrier_raw();
  }

  // epilogue: bias + relu + bf16 store (same C/D layout as proven kernel)
  const int col0 = n0 + wc * 64;
  float bv[4];
#pragma unroll
  for (int ni = 0; ni < 4; ni++)
    bv[ni] = bias[(size_t)e * DHID + col0 + ni * 16 + l15];
#pragma unroll
  for (int mi8 = 0; mi8 < 8; mi8++) {
#pragma unroll
    for (int r = 0; r < 4; r++) {
      const int ml = wr * 128 + mi8 * 16 + quad * 4 + r;
      if (ml >= valid) continue;
      u16* orow = Hout + (size_t)(base_p + ml) * DHID + col0;
#pragma unroll
      for (int ni = 0; ni < 4; ni++) {
        float v = acc[mi8][ni][r] + bv[ni];
        v = v > 0.f ? v : 0.f;
        orow[ni * 16 + l15] = f2b(v);
      }
    }
  }
#undef STG
#undef RDA
#undef RDB2
#undef MM
}

__global__ void sentinel_kernel(float* __restrict__ out, int n) {
  int i = blockIdx.x * blockDim.x + threadIdx.x;
  if (i < n) out[i] = 31337.0f;
}

extern "C" void kernel_launch(void* const* d_in, const int* in_sizes, int n_in,
                              void* d_out, int out_size, void* d_ws, size_t ws_size,
                              hipStream_t stream) {
  const float* x  = (const float*)d_in[0];
  const float* Wr = (const float*)d_in[1];
  const float* br = (const float*)d_in[2];
  const float* W1 = (const float*)d_in[3];
  const float* b1 = (const float*)d_in[4];
  const float* W2 = (const float*)d_in[5];
  const float* b2 = (const float*)d_in[6];
  float* out = (float*)d_out;

  const size_t szXb  = (size_t)NT * DIN * 2;
  const size_t szW1t = (size_t)NE * DIN * DHID * 2;
  const size_t szW2t = (size_t)NE * DHID * DOUT * 2;
  const size_t szHid = (size_t)NT * DHID * 2;
  char* ws = (char*)d_ws;
  u16* Xb   = (u16*)ws;
  u16* W1t  = (u16*)(ws + szXb);
  u16* W2t  = (u16*)(ws + szXb + szW1t);
  u16* Hid  = (u16*)(ws + szXb + szW1t + szW2t);
  int* perm = (int*)(ws + szXb + szW1t + szW2t + szHid);
  int* eidx = perm + NT;
  int* ctrl = eidx + NT;
  int* counts  = ctrl;
  int* cursor  = ctrl + 8;
  int* offsets = ctrl + 16;
  int4* tiles   = (int4*)(ctrl + 32);
  int4* tiles2  = tiles + NMT;     // (136+72)*16B fits the 4KB pad
  const size_t NEED = szXb + szW1t + szW2t + szHid + (size_t)NT * 4 * 2 + 4096;

  if (ws_size < NEED) {
    sentinel_kernel<<<(out_size + 255) / 256, 256, 0, stream>>>(out, out_size);
    return;
  }

  zero_kernel<<<1, 64, 0, stream>>>(ctrl);
  transpose_cvt_all<<<NE * 16 * 64 * 2, 256, 0, stream>>>(W1, W2, W1t, W2t);
  router_kernel<<<NT / 4, 256, 0, stream>>>(x, Wr, br, Xb, eidx, counts);
  scan_kernel<<<1, 64, 0, stream>>>(counts, offsets, tiles, tiles2);
  scatter_kernel<<<NT / 256, 256, 0, stream>>>(eidx, offsets, cursor, perm);

  // GEMM1: hidden[p][h] = relu(Xb[perm[p]] @ W1[e] + b1[e]), bf16 — 8-phase 256^2
  moe_gemm1_8ph<<<16 * NMT2, 512, 0, stream>>>(Xb, W1t, b1, perm, tiles2, Hid);
  // GEMM2: out[perm[p]][o] = hidden[p] @ W2[e] + b2[e], fp32 — 2-phase 128^2
  moe_gemm2<<<8 * NMT, 256, 0, stream>>>(Hid, W2t, b2, perm, tiles, out);
}